// Round 3
// baseline (349.818 us; speedup 1.0000x reference)
//
#include <hip/hip_runtime.h>

// ---------------------------------------------------------------------------
// GGNN message passing, MI355X/gfx950.  Round 12 == Round 11 resubmit
// (R11 bench died with "container failed twice" -- broker-level error;
//  source re-audited: no OOB r/w, no divergent barriers, no unbounded
//  loops; MFMA layouts match R5/R10 harness-verified mappings).
//   - agg_gru v2: barrier-light direct-fragment GEMM.  128-node tile,
//     8 waves.  Phase A: wave owns 16 nodes x 128 cols; A-frags (S) loaded
//     DIRECT from global in MFMA layout (S read once from HBM), B-frags (Wc)
//     from L2 -- zero barriers in the K loop.  Handoff via XOR-swizzled
//     Xagg[128][128] (col ^= (row&7)<<3; conflict-free b128 reads), ONE
//     barrier.  Phase B: 2 passes of 64 nodes, Wg + h frags direct from
//     L2/L3, agg from LDS; fast GRU epilogue; XOR-swizzled f32 Outs tile,
//     coalesced float4 stores.  LDS exactly 64KB -> 2 blocks/CU (16 waves).
//   - gather_s v4: flat 8-deep chunks across segment boundaries; typed sums
//     via snapshots at wave-uniform (readfirstlane) boundary checks.
//     Guarantees MLP=8 (R9's per-segment loops degenerated to MLP~1 at
//     avg 3.1 edges/segment).
// Lessons kept: no gather-into-GEMM fusion (R6); no K-merging (R7);
// LDS-staged coalesced epilogue stores (R5); (dst,type) CSR (R6/R9).
// ---------------------------------------------------------------------------

typedef __attribute__((ext_vector_type(8))) short short8;
typedef __attribute__((ext_vector_type(4))) float floatx4;

#define HID 128
#define NTY 4

__device__ __forceinline__ unsigned short f2bf(float f) {
    unsigned int u = __float_as_uint(f);
    unsigned int r = (u + 0x7fffu + ((u >> 16) & 1u)) >> 16;  // RNE
    return (unsigned short)r;
}
__device__ __forceinline__ float bf2f(unsigned int lo16) {
    return __uint_as_float(lo16 << 16);
}
__device__ __forceinline__ float frcp(float x) { return __builtin_amdgcn_rcpf(x); }

// ---- prep: cvt_h | pack_wcat | pack_wgru | bias4 | zero deg4 --------------

__global__ void prep_kernel(const float* __restrict__ h, unsigned short* __restrict__ hbf,
                            const float* __restrict__ W, unsigned short* __restrict__ Wc,
                            const float* __restrict__ w_ih, const float* __restrict__ w_hh,
                            unsigned short* __restrict__ Wg, float* __restrict__ bias4,
                            const float* __restrict__ b_ih, const float* __restrict__ b_hh,
                            int* __restrict__ deg4, int total4, int nb_cvt, int N4) {
    int b = blockIdx.x, tt = threadIdx.x;
    if (b < nb_cvt) {
        int i = b * 256 + tt;
        if (i < total4) {
            float4 v = ((const float4*)h)[i];
            uint2 o;
            o.x = (unsigned int)f2bf(v.x) | ((unsigned int)f2bf(v.y) << 16);
            o.y = (unsigned int)f2bf(v.z) | ((unsigned int)f2bf(v.w) << 16);
            ((uint2*)hbf)[i] = o;
        }
    } else if (b < nb_cvt + 256) {
        // Wcat[j][t*128+k] = edge_W[t][j][k]  (128 x 512)
        int idx = (b - nb_cvt) * 256 + tt;
        int j = idx >> 9, rem = idx & 511;
        int t = rem >> 7, k = rem & 127;
        Wc[idx] = f2bf(W[(t * HID + j) * HID + k]);
    } else if (b < nb_cvt + 768) {
        // Wg[512][256]: rows 4j+{0,1,2,3} = r|z|i_n|h_n; cols 0-127 agg, 128-255 h
        int idx = (b - nb_cvt - 256) * 256 + tt;
        int row = idx >> 8, k = idx & 255;
        int j = row >> 2, g = row & 3;
        float v = 0.0f;
        if (g == 0) v = (k < 128) ? w_ih[j * 128 + k]         : w_hh[j * 128 + (k - 128)];
        else if (g == 1) v = (k < 128) ? w_ih[(128 + j) * 128 + k] : w_hh[(128 + j) * 128 + (k - 128)];
        else if (g == 2) v = (k < 128) ? w_ih[(256 + j) * 128 + k] : 0.0f;
        else             v = (k < 128) ? 0.0f : w_hh[(256 + j) * 128 + (k - 128)];
        Wg[idx] = f2bf(v);
    } else if (b == nb_cvt + 768) {
        if (tt < 128) {
            float4 v;
            v.x = b_ih[tt] + b_hh[tt];
            v.y = b_ih[128 + tt] + b_hh[128 + tt];
            v.z = b_ih[256 + tt];
            v.w = b_hh[256 + tt];
            ((float4*)bias4)[tt] = v;
        }
    } else {
        int i = (b - nb_cvt - 769) * 256 + tt;
        if (i < N4) deg4[i] = 0;
    }
}

// ---- (dst,type)-segmented CSR construction (R6, verified) -----------------

__global__ void hist4_kernel(const int* __restrict__ dst, const int* __restrict__ ety,
                             int* __restrict__ deg4, int E) {
    int e = blockIdx.x * blockDim.x + threadIdx.x;
    if (e < E) atomicAdd(&deg4[dst[e] * 4 + ety[e]], 1);
}

__global__ void scan_blocks4_kernel(const int* __restrict__ deg, int* __restrict__ rowptr,
                                    int* __restrict__ blocksum, int N4) {
    __shared__ int s[256];
    int t = threadIdx.x;
    int base = blockIdx.x * 1024 + t * 4;
    int v0 = 0, v1 = 0, v2 = 0, v3 = 0;
    if (base + 3 < N4) {
        v0 = deg[base]; v1 = deg[base + 1]; v2 = deg[base + 2]; v3 = deg[base + 3];
    } else {
        if (base < N4) v0 = deg[base];
        if (base + 1 < N4) v1 = deg[base + 1];
        if (base + 2 < N4) v2 = deg[base + 2];
    }
    int sum = v0 + v1 + v2 + v3;
    s[t] = sum;
    __syncthreads();
#pragma unroll
    for (int off = 1; off < 256; off <<= 1) {
        int x = (t >= off) ? s[t - off] : 0;
        __syncthreads();
        s[t] += x;
        __syncthreads();
    }
    int ex = s[t] - sum;
    if (base < N4) rowptr[base] = ex;
    if (base + 1 < N4) rowptr[base + 1] = ex + v0;
    if (base + 2 < N4) rowptr[base + 2] = ex + v0 + v1;
    if (base + 3 < N4) rowptr[base + 3] = ex + v0 + v1 + v2;
    if (t == 255) blocksum[blockIdx.x] = s[255];
}

__global__ void scan_top_kernel(const int* __restrict__ blocksum, int* __restrict__ blockoff, int nb) {
    __shared__ int s[256];
    int t = threadIdx.x;
    int v = (t < nb) ? blocksum[t] : 0;
    s[t] = v;
    __syncthreads();
#pragma unroll
    for (int off = 1; off < 256; off <<= 1) {
        int x = (t >= off) ? s[t - off] : 0;
        __syncthreads();
        s[t] += x;
        __syncthreads();
    }
    if (t < nb) blockoff[t] = s[t] - v;
}

__global__ void finalize4_kernel(int* __restrict__ rowptr, const int* __restrict__ blockoff,
                                 int* __restrict__ cursor, int N4, int E) {
    int i = blockIdx.x * blockDim.x + threadIdx.x;
    if (i >= N4) return;
    int r = rowptr[i] + blockoff[i >> 10];
    rowptr[i] = r;
    cursor[i] = r;
    if (i == 0) rowptr[N4] = E;  // sentinel
}

__global__ void fill4_kernel(const int* __restrict__ src, const int* __restrict__ dst,
                             const int* __restrict__ ety, int* __restrict__ cursor,
                             int* __restrict__ csr, int E) {
    int e = blockIdx.x * blockDim.x + threadIdx.x;
    if (e >= E) return;
    int pos = atomicAdd(&cursor[dst[e] * 4 + ety[e]], 1);
    csr[pos] = src[e];
}

// ---- gather_s v4: flat MLP-8 chunks + uniform boundary snapshots ----------

__global__ void gather_s_kernel(const int* __restrict__ rowptr4, const int* __restrict__ csr,
                                const unsigned int* __restrict__ hbu,
                                float4* __restrict__ cnt4, unsigned int* __restrict__ Su, int N) {
    int w = blockIdx.x * (blockDim.x >> 6) + (threadIdx.x >> 6);
    if (w >= N) return;
    int lane = threadIdx.x & 63;
    int b0 = __builtin_amdgcn_readfirstlane(rowptr4[w * 4]);
    int b1 = __builtin_amdgcn_readfirstlane(rowptr4[w * 4 + 1]);
    int b2 = __builtin_amdgcn_readfirstlane(rowptr4[w * 4 + 2]);
    int b3 = __builtin_amdgcn_readfirstlane(rowptr4[w * 4 + 3]);
    int b4 = __builtin_amdgcn_readfirstlane(rowptr4[w * 4 + 4]);  // sentinel-backed

    float s0 = 0.f, s1 = 0.f;
    float sn0[3], sn1[3];

    int e = b0;
    while (e + 8 <= b4) {
        int p[8];
        unsigned int u[8];
#pragma unroll
        for (int i = 0; i < 8; ++i) p[i] = csr[e + i];
#pragma unroll
        for (int i = 0; i < 8; ++i) u[i] = hbu[(size_t)p[i] * 64 + lane];
#pragma unroll
        for (int i = 0; i < 8; ++i) {
            int idx = e + i;
            if (idx == b1) { sn0[0] = s0; sn1[0] = s1; }
            if (idx == b2) { sn0[1] = s0; sn1[1] = s1; }
            if (idx == b3) { sn0[2] = s0; sn1[2] = s1; }
            s0 += bf2f(u[i] & 0xffffu);
            s1 += bf2f(u[i] >> 16);
        }
        e += 8;
    }
    {   // tail: 0..7 edges, uniform predication
        int rem = b4 - e;
        int p[7];
        unsigned int u[7];
#pragma unroll
        for (int i = 0; i < 7; ++i) if (i < rem) p[i] = csr[e + i];
#pragma unroll
        for (int i = 0; i < 7; ++i) if (i < rem) u[i] = hbu[(size_t)p[i] * 64 + lane];
#pragma unroll
        for (int i = 0; i < 7; ++i) {
            if (i < rem) {
                int idx = e + i;
                if (idx == b1) { sn0[0] = s0; sn1[0] = s1; }
                if (idx == b2) { sn0[1] = s0; sn1[1] = s1; }
                if (idx == b3) { sn0[2] = s0; sn1[2] = s1; }
                s0 += bf2f(u[i] & 0xffffu);
                s1 += bf2f(u[i] >> 16);
            }
        }
    }
    if (b1 == b4) { sn0[0] = s0; sn1[0] = s1; }
    if (b2 == b4) { sn0[1] = s0; sn1[1] = s1; }
    if (b3 == b4) { sn0[2] = s0; sn1[2] = s1; }

    size_t base = (size_t)w * 256 + lane;
    float a0, a1, p0 = 0.f, p1 = 0.f;
#pragma unroll
    for (int t = 0; t < 4; ++t) {
        float c0 = (t < 3) ? sn0[t] : s0;
        float c1 = (t < 3) ? sn1[t] : s1;
        a0 = c0 - p0; a1 = c1 - p1;
        p0 = c0; p1 = c1;
        Su[base + t * 64] = (unsigned int)f2bf(a0) | ((unsigned int)f2bf(a1) << 16);
    }
    if (lane == 0)
        cnt4[w] = make_float4((float)(b1 - b0), (float)(b2 - b1),
                              (float)(b3 - b2), (float)(b4 - b3));
}

// ---- agg_gru v2: fused  agg = S @ Wcat^T (+cnt.eb)  ->  GRU -> out --------

__global__ __launch_bounds__(512, 4) void agg_gru(const unsigned short* __restrict__ S,
                                                  const unsigned short* __restrict__ Wc,
                                                  const unsigned short* __restrict__ Wg,
                                                  const unsigned short* __restrict__ hbf,
                                                  const float4* __restrict__ cnt4,
                                                  const float* __restrict__ eb,
                                                  const float4* __restrict__ bias4,
                                                  float* __restrict__ out, int M) {
    __shared__ __align__(16) unsigned short Xagg[128][128];  // 32KB, XOR-swizzled
    __shared__ __align__(16) float Outs[64][128];            // 32KB, XOR-swizzled

    const int tid = threadIdx.x;
    const int m0 = blockIdx.x * 128;
    const int lane = tid & 63, w = tid >> 6;
    const int lm = lane & 15, quad = lane >> 4;

    // ---- phase A: no barriers, direct fragment loads ----
    floatx4 accA[8];
#pragma unroll
    for (int n = 0; n < 8; ++n) accA[n] = (floatx4){0.f, 0.f, 0.f, 0.f};

    int arow = m0 + w * 16 + lm;
    if (arow >= M) arow = M - 1;
    const unsigned short* Sp = S + (size_t)arow * 512 + quad * 8;

#pragma unroll
    for (int ks = 0; ks < 16; ++ks) {
        short8 av = *(const short8*)(Sp + ks * 32);
#pragma unroll
        for (int n = 0; n < 8; ++n) {
            short8 bw = *(const short8*)(Wc + (size_t)(n * 16 + lm) * 512 + ks * 32 + quad * 8);
            accA[n] = __builtin_amdgcn_mfma_f32_16x16x32_bf16(av, bw, accA[n], 0, 0, 0);
        }
    }

    // handoff: agg(+cnt.eb) -> Xagg (bf16, swizzled)
    {
        float4 c4v[4];
#pragma unroll
        for (int r = 0; r < 4; ++r) {
            int gn = m0 + w * 16 + quad * 4 + r;
            if (gn >= M) gn = M - 1;
            c4v[r] = cnt4[gn];
        }
#pragma unroll
        for (int n = 0; n < 8; ++n) {
            int j = n * 16 + lm;
            float e0 = eb[j], e1 = eb[HID + j], e2 = eb[2 * HID + j], e3 = eb[3 * HID + j];
#pragma unroll
            for (int r = 0; r < 4; ++r) {
                int nl = w * 16 + quad * 4 + r;
                float v = accA[n][r] + c4v[r].x * e0 + c4v[r].y * e1 + c4v[r].z * e2 + c4v[r].w * e3;
                Xagg[nl][j ^ ((nl & 7) << 3)] = f2bf(v);
            }
        }
    }
    __syncthreads();

    // ---- phase B: 2 passes of 64 nodes ----
#pragma unroll 1
    for (int p = 0; p < 2; ++p) {
        floatx4 accB[4][4];
#pragma unroll
        for (int a = 0; a < 4; ++a)
#pragma unroll
            for (int b = 0; b < 4; ++b) accB[a][b] = (floatx4){0.f, 0.f, 0.f, 0.f};

#pragma unroll
        for (int ss = 0; ss < 8; ++ss) {
            short8 bfr[4];
#pragma unroll
            for (int ni = 0; ni < 4; ++ni) {
                if (ss < 4) {
                    int row = p * 64 + ni * 16 + lm;
                    int col = (ss * 32 + quad * 8) ^ ((lm & 7) << 3);
                    bfr[ni] = *(const short8*)&Xagg[row][col];
                } else {
                    int gr = m0 + p * 64 + ni * 16 + lm;
                    if (gr >= M) gr = M - 1;
                    bfr[ni] = *(const short8*)(hbf + (size_t)gr * HID + (ss - 4) * 32 + quad * 8);
                }
            }
            short8 af[4];
#pragma unroll
            for (int mi = 0; mi < 4; ++mi)
                af[mi] = *(const short8*)(Wg + (size_t)(w * 64 + mi * 16 + lm) * 256 + ss * 32 + quad * 8);
#pragma unroll
            for (int mi = 0; mi < 4; ++mi)
#pragma unroll
                for (int ni = 0; ni < 4; ++ni)
                    accB[mi][ni] = __builtin_amdgcn_mfma_f32_16x16x32_bf16(af[mi], bfr[ni], accB[mi][ni], 0, 0, 0);
        }

        // GRU epilogue -> Outs (swizzled f32)
#pragma unroll
        for (int mi = 0; mi < 4; ++mi) {
            int j = w * 16 + mi * 4 + quad;   // 0..127
            float4 bb = bias4[j];             // {b_r, b_z, b_in, b_hn}
#pragma unroll
            for (int ni = 0; ni < 4; ++ni) {
                int nl = ni * 16 + lm;
                int gn = m0 + p * 64 + nl;
                int gc = (gn >= M) ? (M - 1) : gn;
                float g0 = accB[mi][ni][0], g1 = accB[mi][ni][1];
                float g2 = accB[mi][ni][2], g3 = accB[mi][ni][3];
                float rr = frcp(1.f + __expf(-(g0 + bb.x)));
                float zz = frcp(1.f + __expf(-(g1 + bb.y)));
                float aa = g2 + bb.z + rr * (g3 + bb.w);
                float nn = 1.f - 2.f * frcp(1.f + __expf(2.f * aa));  // tanh
                float hv = bf2f((unsigned int)hbf[(size_t)gc * HID + j]);
                Outs[nl][j ^ ((nl & 7) << 2)] = nn + zz * (hv - nn);
            }
        }
        __syncthreads();

        // coalesced store: 64 nodes x 128 floats
        {
            int row = tid >> 3;              // 0..63
            int c0 = (tid & 7) * 16;         // 0..112
            int node = m0 + p * 64 + row;
            if (node < M) {
                float* dstp = out + (size_t)node * HID;
#pragma unroll
                for (int i = 0; i < 4; ++i) {
                    int c = c0 + i * 4;
                    *(float4*)(dstp + c) = *(const float4*)&Outs[row][c ^ ((row & 7) << 2)];
                }
            }
        }
        __syncthreads();  // protect Outs reuse by pass 1
    }
}

// ---------------------------------------------------------------------------

extern "C" void kernel_launch(void* const* d_in, const int* in_sizes, int n_in,
                              void* d_out, int out_size, void* d_ws, size_t ws_size,
                              hipStream_t stream) {
    const float* node_states = (const float*)d_in[0];
    const int*   edge_index  = (const int*)d_in[1];
    const int*   edge_type   = (const int*)d_in[2];
    const float* edge_W      = (const float*)d_in[3];
    const float* edge_b      = (const float*)d_in[4];
    const float* w_ih        = (const float*)d_in[5];
    const float* w_hh        = (const float*)d_in[6];
    const float* b_ih        = (const float*)d_in[7];
    const float* b_hh        = (const float*)d_in[8];

    const int M = in_sizes[0] / HID;      // 50000 nodes
    const int E = in_sizes[1] / 2;        // 625000 edges
    const int N4 = M * 4;                 // 200000 (dst,type) segments
    const int* src = edge_index;
    const int* dst = edge_index + E;

    // workspace layout (~70 MB)
    char* ws = (char*)d_ws;
    size_t off = 0;
    unsigned short* hbf   = (unsigned short*)(ws + off); off += (size_t)M * HID * 2;    // 12.8MB
    float*          bias4 = (float*)(ws + off);          off += (size_t)128 * 4 * 4;    // 2KB
    unsigned short* S     = (unsigned short*)(ws + off); off += (size_t)M * 512 * 2;    // 51.2MB
    unsigned short* Wcat  = (unsigned short*)(ws + off); off += (size_t)128 * 512 * 2;  // 128KB
    unsigned short* Wgru  = (unsigned short*)(ws + off); off += (size_t)512 * 256 * 2;  // 256KB
    float*          cnt4  = (float*)(ws + off);          off += (size_t)M * 4 * 4;      // 800KB
    int* deg4     = (int*)(ws + off); off += (size_t)N4 * 4;
    int* rowptr4  = (int*)(ws + off); off += (size_t)(N4 + 1) * 4;
    int* cursor4  = (int*)(ws + off); off += (size_t)N4 * 4;
    int* blocksum = (int*)(ws + off); off += 256 * 4;
    int* blockoff = (int*)(ws + off); off += 256 * 4;
    int* csr      = (int*)(ws + off); off += (size_t)E * 4;

    const int total4 = M * HID / 4;
    const int nb_cvt = (total4 + 255) / 256;     // 6250
    const int nb_zero = (N4 + 255) / 256;        // 782
    const int nb_scan = (N4 + 1023) / 1024;      // 196 <= 256

    prep_kernel<<<nb_cvt + 769 + nb_zero, 256, 0, stream>>>(
        node_states, hbf, edge_W, Wcat, w_ih, w_hh, Wgru, bias4, b_ih, b_hh,
        deg4, total4, nb_cvt, N4);

    hist4_kernel<<<(E + 255) / 256, 256, 0, stream>>>(dst, edge_type, deg4, E);
    scan_blocks4_kernel<<<nb_scan, 256, 0, stream>>>(deg4, rowptr4, blocksum, N4);
    scan_top_kernel<<<1, 256, 0, stream>>>(blocksum, blockoff, nb_scan);
    finalize4_kernel<<<(N4 + 255) / 256, 256, 0, stream>>>(rowptr4, blockoff, cursor4, N4, E);
    fill4_kernel<<<(E + 255) / 256, 256, 0, stream>>>(src, dst, edge_type, cursor4, csr, E);

    gather_s_kernel<<<(M + 3) / 4, 256, 0, stream>>>(rowptr4, csr, (const unsigned int*)hbf,
                                                     (float4*)cnt4, (unsigned int*)S, M);

    agg_gru<<<(M + 127) / 128, 512, 0, stream>>>(S, Wcat, Wgru, hbf, (const float4*)cnt4,
                                                 edge_b, (const float4*)bias4, (float*)d_out, M);
}

// Round 4
// 273.589 us; speedup vs baseline: 1.2786x; 1.2786x over previous
//
#include <hip/hip_runtime.h>

// ---------------------------------------------------------------------------
// GGNN message passing, MI355X/gfx950.  Round 13:
//   - agg_gru v3 = R10's verified fused kernel + pipelined staging.
//     R12 post-mortem: direct-fragment phase A (8 acc + 9 global streams
//     per lane) spilled under the 128-reg cap -> 327MB scratch traffic,
//     memory-bound at 167us.  LESSON: A-operand must be LDS-staged.
//     v3: 64-node tile, 8 waves; phase A = 4 K-steps, reg-staged
//     double-buffered LDS (issue loads for c+1 BEFORE computing c,
//     unroll 1 -> pipeline stays 2-deep), ONE barrier per step
//     (write->bar->compute; buffer parity covers the WAR hazard).
//     Phase B reads hbf direct from global (L1/L2-hot; the one R12 piece
//     that was fine) -> no h LDS tile.  LDS 52224B.  Epilogue/handoff
//     indices verbatim R10 (harness-verified).
//   - gather_s v4 kept (flat MLP-8 chunks, uniform boundary snapshots).
// Lessons: no gather-into-GEMM fusion (R6); no K-merging (R7); LDS-staged
// coalesced out stores (R5); (dst,type) CSR (R6/R9); no per-lane weight
// streaming (R12).
// ---------------------------------------------------------------------------

typedef __attribute__((ext_vector_type(8))) short short8;
typedef __attribute__((ext_vector_type(4))) float floatx4;

#define HID 128
#define NTY 4

__device__ __forceinline__ unsigned short f2bf(float f) {
    unsigned int u = __float_as_uint(f);
    unsigned int r = (u + 0x7fffu + ((u >> 16) & 1u)) >> 16;  // RNE
    return (unsigned short)r;
}
__device__ __forceinline__ float bf2f(unsigned int lo16) {
    return __uint_as_float(lo16 << 16);
}
__device__ __forceinline__ float frcp(float x) { return __builtin_amdgcn_rcpf(x); }

// ---- prep: cvt_h | pack_wcat | pack_wgru | bias4 | zero deg4 --------------

__global__ void prep_kernel(const float* __restrict__ h, unsigned short* __restrict__ hbf,
                            const float* __restrict__ W, unsigned short* __restrict__ Wc,
                            const float* __restrict__ w_ih, const float* __restrict__ w_hh,
                            unsigned short* __restrict__ Wg, float* __restrict__ bias4,
                            const float* __restrict__ b_ih, const float* __restrict__ b_hh,
                            int* __restrict__ deg4, int total4, int nb_cvt, int N4) {
    int b = blockIdx.x, tt = threadIdx.x;
    if (b < nb_cvt) {
        int i = b * 256 + tt;
        if (i < total4) {
            float4 v = ((const float4*)h)[i];
            uint2 o;
            o.x = (unsigned int)f2bf(v.x) | ((unsigned int)f2bf(v.y) << 16);
            o.y = (unsigned int)f2bf(v.z) | ((unsigned int)f2bf(v.w) << 16);
            ((uint2*)hbf)[i] = o;
        }
    } else if (b < nb_cvt + 256) {
        // Wcat[j][t*128+k] = edge_W[t][j][k]  (128 x 512)
        int idx = (b - nb_cvt) * 256 + tt;
        int j = idx >> 9, rem = idx & 511;
        int t = rem >> 7, k = rem & 127;
        Wc[idx] = f2bf(W[(t * HID + j) * HID + k]);
    } else if (b < nb_cvt + 768) {
        // Wg[512][256]: rows 4j+{0,1,2,3} = r|z|i_n|h_n; cols 0-127 agg, 128-255 h
        int idx = (b - nb_cvt - 256) * 256 + tt;
        int row = idx >> 8, k = idx & 255;
        int j = row >> 2, g = row & 3;
        float v = 0.0f;
        if (g == 0) v = (k < 128) ? w_ih[j * 128 + k]         : w_hh[j * 128 + (k - 128)];
        else if (g == 1) v = (k < 128) ? w_ih[(128 + j) * 128 + k] : w_hh[(128 + j) * 128 + (k - 128)];
        else if (g == 2) v = (k < 128) ? w_ih[(256 + j) * 128 + k] : 0.0f;
        else             v = (k < 128) ? 0.0f : w_hh[(256 + j) * 128 + (k - 128)];
        Wg[idx] = f2bf(v);
    } else if (b == nb_cvt + 768) {
        if (tt < 128) {
            float4 v;
            v.x = b_ih[tt] + b_hh[tt];
            v.y = b_ih[128 + tt] + b_hh[128 + tt];
            v.z = b_ih[256 + tt];
            v.w = b_hh[256 + tt];
            ((float4*)bias4)[tt] = v;
        }
    } else {
        int i = (b - nb_cvt - 769) * 256 + tt;
        if (i < N4) deg4[i] = 0;
    }
}

// ---- (dst,type)-segmented CSR construction (R6, verified) -----------------

__global__ void hist4_kernel(const int* __restrict__ dst, const int* __restrict__ ety,
                             int* __restrict__ deg4, int E) {
    int e = blockIdx.x * blockDim.x + threadIdx.x;
    if (e < E) atomicAdd(&deg4[dst[e] * 4 + ety[e]], 1);
}

__global__ void scan_blocks4_kernel(const int* __restrict__ deg, int* __restrict__ rowptr,
                                    int* __restrict__ blocksum, int N4) {
    __shared__ int s[256];
    int t = threadIdx.x;
    int base = blockIdx.x * 1024 + t * 4;
    int v0 = 0, v1 = 0, v2 = 0, v3 = 0;
    if (base + 3 < N4) {
        v0 = deg[base]; v1 = deg[base + 1]; v2 = deg[base + 2]; v3 = deg[base + 3];
    } else {
        if (base < N4) v0 = deg[base];
        if (base + 1 < N4) v1 = deg[base + 1];
        if (base + 2 < N4) v2 = deg[base + 2];
    }
    int sum = v0 + v1 + v2 + v3;
    s[t] = sum;
    __syncthreads();
#pragma unroll
    for (int off = 1; off < 256; off <<= 1) {
        int x = (t >= off) ? s[t - off] : 0;
        __syncthreads();
        s[t] += x;
        __syncthreads();
    }
    int ex = s[t] - sum;
    if (base < N4) rowptr[base] = ex;
    if (base + 1 < N4) rowptr[base + 1] = ex + v0;
    if (base + 2 < N4) rowptr[base + 2] = ex + v0 + v1;
    if (base + 3 < N4) rowptr[base + 3] = ex + v0 + v1 + v2;
    if (t == 255) blocksum[blockIdx.x] = s[255];
}

__global__ void scan_top_kernel(const int* __restrict__ blocksum, int* __restrict__ blockoff, int nb) {
    __shared__ int s[256];
    int t = threadIdx.x;
    int v = (t < nb) ? blocksum[t] : 0;
    s[t] = v;
    __syncthreads();
#pragma unroll
    for (int off = 1; off < 256; off <<= 1) {
        int x = (t >= off) ? s[t - off] : 0;
        __syncthreads();
        s[t] += x;
        __syncthreads();
    }
    if (t < nb) blockoff[t] = s[t] - v;
}

__global__ void finalize4_kernel(int* __restrict__ rowptr, const int* __restrict__ blockoff,
                                 int* __restrict__ cursor, int N4, int E) {
    int i = blockIdx.x * blockDim.x + threadIdx.x;
    if (i >= N4) return;
    int r = rowptr[i] + blockoff[i >> 10];
    rowptr[i] = r;
    cursor[i] = r;
    if (i == 0) rowptr[N4] = E;  // sentinel
}

__global__ void fill4_kernel(const int* __restrict__ src, const int* __restrict__ dst,
                             const int* __restrict__ ety, int* __restrict__ cursor,
                             int* __restrict__ csr, int E) {
    int e = blockIdx.x * blockDim.x + threadIdx.x;
    if (e >= E) return;
    int pos = atomicAdd(&cursor[dst[e] * 4 + ety[e]], 1);
    csr[pos] = src[e];
}

// ---- gather_s v4: flat MLP-8 chunks + uniform boundary snapshots ----------

__global__ void gather_s_kernel(const int* __restrict__ rowptr4, const int* __restrict__ csr,
                                const unsigned int* __restrict__ hbu,
                                float4* __restrict__ cnt4, unsigned int* __restrict__ Su, int N) {
    int w = blockIdx.x * (blockDim.x >> 6) + (threadIdx.x >> 6);
    if (w >= N) return;
    int lane = threadIdx.x & 63;
    int b0 = __builtin_amdgcn_readfirstlane(rowptr4[w * 4]);
    int b1 = __builtin_amdgcn_readfirstlane(rowptr4[w * 4 + 1]);
    int b2 = __builtin_amdgcn_readfirstlane(rowptr4[w * 4 + 2]);
    int b3 = __builtin_amdgcn_readfirstlane(rowptr4[w * 4 + 3]);
    int b4 = __builtin_amdgcn_readfirstlane(rowptr4[w * 4 + 4]);  // sentinel-backed

    float s0 = 0.f, s1 = 0.f;
    float sn0[3], sn1[3];

    int e = b0;
    while (e + 8 <= b4) {
        int p[8];
        unsigned int u[8];
#pragma unroll
        for (int i = 0; i < 8; ++i) p[i] = csr[e + i];
#pragma unroll
        for (int i = 0; i < 8; ++i) u[i] = hbu[(size_t)p[i] * 64 + lane];
#pragma unroll
        for (int i = 0; i < 8; ++i) {
            int idx = e + i;
            if (idx == b1) { sn0[0] = s0; sn1[0] = s1; }
            if (idx == b2) { sn0[1] = s0; sn1[1] = s1; }
            if (idx == b3) { sn0[2] = s0; sn1[2] = s1; }
            s0 += bf2f(u[i] & 0xffffu);
            s1 += bf2f(u[i] >> 16);
        }
        e += 8;
    }
    {   // tail: 0..7 edges, uniform predication
        int rem = b4 - e;
        int p[7];
        unsigned int u[7];
#pragma unroll
        for (int i = 0; i < 7; ++i) if (i < rem) p[i] = csr[e + i];
#pragma unroll
        for (int i = 0; i < 7; ++i) if (i < rem) u[i] = hbu[(size_t)p[i] * 64 + lane];
#pragma unroll
        for (int i = 0; i < 7; ++i) {
            if (i < rem) {
                int idx = e + i;
                if (idx == b1) { sn0[0] = s0; sn1[0] = s1; }
                if (idx == b2) { sn0[1] = s0; sn1[1] = s1; }
                if (idx == b3) { sn0[2] = s0; sn1[2] = s1; }
                s0 += bf2f(u[i] & 0xffffu);
                s1 += bf2f(u[i] >> 16);
            }
        }
    }
    if (b1 == b4) { sn0[0] = s0; sn1[0] = s1; }
    if (b2 == b4) { sn0[1] = s0; sn1[1] = s1; }
    if (b3 == b4) { sn0[2] = s0; sn1[2] = s1; }

    size_t base = (size_t)w * 256 + lane;
    float a0, a1, p0 = 0.f, p1 = 0.f;
#pragma unroll
    for (int t = 0; t < 4; ++t) {
        float c0 = (t < 3) ? sn0[t] : s0;
        float c1 = (t < 3) ? sn1[t] : s1;
        a0 = c0 - p0; a1 = c1 - p1;
        p0 = c0; p1 = c1;
        Su[base + t * 64] = (unsigned int)f2bf(a0) | ((unsigned int)f2bf(a1) << 16);
    }
    if (lane == 0)
        cnt4[w] = make_float4((float)(b1 - b0), (float)(b2 - b1),
                              (float)(b3 - b2), (float)(b4 - b3));
}

// ---- agg_gru v3: R10 structure + pipelined double-buffered staging --------
// 64-node tile, 512 threads (8 waves).
// Phase A: wave w owns agg cols [w*16,+16); K=512 in 4 BK=128 steps.
//   Step c: (issue global loads for c+1) -> ds_write regs(c) -> barrier ->
//   16 MFMA from Sb[c&1].  ONE barrier/step (buffer parity covers WAR).
// Handoff: agg(+cnt.eb) -> Xagg[64][136] bf16 (R10-verified indices); bar.
// Phase B: no barriers.  K=256: ss 0-3 agg from LDS, ss 4-7 h direct from
//   hbf (L1/L2-hot).  Wg frags in-loop from L2.  accB[4][4] gates packed.
// Epilogue: fast sigmoid/tanh; hv direct from hbf; f32 Outs tile (overlays
//   Sb after the handoff barrier); coalesced float4 stores.

__global__ __launch_bounds__(512, 4) void agg_gru(const unsigned short* __restrict__ S,
                                                  const unsigned short* __restrict__ Wc,
                                                  const unsigned short* __restrict__ Wg,
                                                  const unsigned short* __restrict__ hbf,
                                                  const float4* __restrict__ cnt4,
                                                  const float* __restrict__ eb,
                                                  const float4* __restrict__ bias4,
                                                  float* __restrict__ out, int M) {
    __shared__ __align__(16) unsigned char smem[52224];
    typedef unsigned short row136[136];
    row136* Sb0  = (row136*)smem;                  // [64][136]  17408B
    row136* Sb1  = (row136*)(smem + 17408);        // [64][136]  17408B
    row136* Xagg = (row136*)(smem + 34816);        // [64][136]  17408B
    float (*Outs)[132] = (float (*)[132])smem;     // overlay on Sb (33792B)

    const int tid = threadIdx.x;
    const int m0 = blockIdx.x * 64;
    const int lane = tid & 63, w = tid >> 6;
    const int lm = lane & 15, quad = lane >> 4;

    // staging geometry: thread stages rows {r0, r0+32} x 8 shorts at col sc
    const int r0 = tid >> 4, sc = (tid & 15) * 8;
    const int gA = m0 + r0, gB = m0 + 32 + r0;
    const bool vA = gA < M, vB = gB < M;
    const unsigned short* SpA = S + (size_t)(vA ? gA : 0) * 512 + sc;
    const unsigned short* SpB = S + (size_t)(vB ? gB : 0) * 512 + sc;
    const uint4 Z = {0u, 0u, 0u, 0u};

    uint4 c0v = vA ? *(const uint4*)SpA : Z;     // chunk c=0 in regs
    uint4 c1v = vB ? *(const uint4*)SpB : Z;

    floatx4 accA[4];
#pragma unroll
    for (int a = 0; a < 4; ++a) accA[a] = (floatx4){0.f, 0.f, 0.f, 0.f};

#pragma unroll 1
    for (int c = 0; c < 4; ++c) {
        uint4 n0v = Z, n1v = Z;
        if (c < 3) {                              // issue next-step loads EARLY
            n0v = vA ? *(const uint4*)(SpA + (c + 1) * 128) : Z;
            n1v = vB ? *(const uint4*)(SpB + (c + 1) * 128) : Z;
        }
        row136* buf = (c & 1) ? Sb1 : Sb0;
        *(uint4*)&buf[r0][sc] = c0v;
        *(uint4*)&buf[32 + r0][sc] = c1v;
        __syncthreads();                          // staging visible
#pragma unroll
        for (int ss = 0; ss < 4; ++ss) {
            short8 bw = *(const short8*)(Wc + (size_t)(w * 16 + lm) * 512 + c * 128 + ss * 32 + quad * 8);
#pragma unroll
            for (int mi = 0; mi < 4; ++mi) {
                short8 av = *(const short8*)&buf[mi * 16 + lm][ss * 32 + quad * 8];
                accA[mi] = __builtin_amdgcn_mfma_f32_16x16x32_bf16(av, bw, accA[mi], 0, 0, 0);
            }
        }
        c0v = n0v; c1v = n1v;
        // no trailing barrier: next step writes the OTHER buffer; the write
        // two steps ahead is ordered by the intervening step's barrier.
    }

    // handoff: agg(+cnt.eb) -> Xagg (bf16).  D: row nl=mi*16+quad*4+r,
    // col j=w*16+lm  (R10 harness-verified mapping).
    {
        int j = w * 16 + lm;
        float e0 = eb[j], e1 = eb[HID + j], e2 = eb[2 * HID + j], e3 = eb[3 * HID + j];
#pragma unroll
        for (int mi = 0; mi < 4; ++mi) {
#pragma unroll
            for (int r = 0; r < 4; ++r) {
                int nl = mi * 16 + quad * 4 + r;
                int gn = m0 + nl;
                if (gn >= M) gn = M - 1;
                float4 c4 = cnt4[gn];
                float v = accA[mi][r] + c4.x * e0 + c4.y * e1 + c4.z * e2 + c4.w * e3;
                Xagg[nl][j] = f2bf(v);
            }
        }
    }
    __syncthreads();  // Xagg complete; all waves past phase A (Sb dead)

    // ---- phase B: gates[512 x 64] = Wg @ [agg|h]^T, K=256, no barriers ----
    floatx4 accB[4][4];
#pragma unroll
    for (int a = 0; a < 4; ++a)
#pragma unroll
        for (int b = 0; b < 4; ++b) accB[a][b] = (floatx4){0.f, 0.f, 0.f, 0.f};

#pragma unroll
    for (int ss = 0; ss < 8; ++ss) {
        short8 bfr[4];
#pragma unroll
        for (int ni = 0; ni < 4; ++ni) {
            if (ss < 4) {
                bfr[ni] = *(const short8*)&Xagg[ni * 16 + lm][ss * 32 + quad * 8];
            } else {
                int gr = m0 + ni * 16 + lm;
                if (gr >= M) gr = M - 1;
                bfr[ni] = *(const short8*)(hbf + (size_t)gr * HID + (ss - 4) * 32 + quad * 8);
            }
        }
        short8 af[4];
#pragma unroll
        for (int mi = 0; mi < 4; ++mi)
            af[mi] = *(const short8*)(Wg + (size_t)(w * 64 + mi * 16 + lm) * 256 + ss * 32 + quad * 8);
#pragma unroll
        for (int mi = 0; mi < 4; ++mi)
#pragma unroll
            for (int ni = 0; ni < 4; ++ni)
                accB[mi][ni] = __builtin_amdgcn_mfma_f32_16x16x32_bf16(af[mi], bfr[ni], accB[mi][ni], 0, 0, 0);
    }

    // GRU epilogue -> Outs.  gate row = w*64+mi*16+quad*4+g -> j = row>>2,
    // g = reg (R10 harness-verified).
#pragma unroll
    for (int mi = 0; mi < 4; ++mi) {
        int j = w * 16 + mi * 4 + quad;   // 0..127
        float4 bb = bias4[j];             // {b_r, b_z, b_in, b_hn}
#pragma unroll
        for (int ni = 0; ni < 4; ++ni) {
            int nl = ni * 16 + lm;
            int gn = m0 + nl;
            int gc = (gn >= M) ? (M - 1) : gn;
            float g0 = accB[mi][ni][0], g1 = accB[mi][ni][1];
            float g2 = accB[mi][ni][2], g3 = accB[mi][ni][3];
            float rr = frcp(1.f + __expf(-(g0 + bb.x)));
            float zz = frcp(1.f + __expf(-(g1 + bb.y)));
            float aa = g2 + bb.z + rr * (g3 + bb.w);
            float nn = 1.f - 2.f * frcp(1.f + __expf(2.f * aa));  // tanh
            float hv = bf2f((unsigned int)hbf[(size_t)gc * HID + j]);
            Outs[nl][j] = nn + zz * (hv - nn);
        }
    }
    __syncthreads();  // Outs complete (Sb region; all waves past phase A)

    // coalesced store: 64 nodes x 128 floats (128B per 8 lanes)
    {
        int row = tid >> 3;              // 0..63
        int cb = (tid & 7) * 16;         // 0..112
        int node = m0 + row;
        if (node < M) {
            float* dstp = out + (size_t)node * HID + cb;
#pragma unroll
            for (int i = 0; i < 4; ++i)
                *(float4*)(dstp + i * 4) = *(const float4*)&Outs[row][cb + i * 4];
        }
    }
}

// ---------------------------------------------------------------------------

extern "C" void kernel_launch(void* const* d_in, const int* in_sizes, int n_in,
                              void* d_out, int out_size, void* d_ws, size_t ws_size,
                              hipStream_t stream) {
    const float* node_states = (const float*)d_in[0];
    const int*   edge_index  = (const int*)d_in[1];
    const int*   edge_type   = (const int*)d_in[2];
    const float* edge_W      = (const float*)d_in[3];
    const float* edge_b      = (const float*)d_in[4];
    const float* w_ih        = (const float*)d_in[5];
    const float* w_hh        = (const float*)d_in[6];
    const float* b_ih        = (const float*)d_in[7];
    const float* b_hh        = (const float*)d_in[8];

    const int M = in_sizes[0] / HID;      // 50000 nodes
    const int E = in_sizes[1] / 2;        // 625000 edges
    const int N4 = M * 4;                 // 200000 (dst,type) segments
    const int* src = edge_index;
    const int* dst = edge_index + E;

    // workspace layout (~70 MB)
    char* ws = (char*)d_ws;
    size_t off = 0;
    unsigned short* hbf   = (unsigned short*)(ws + off); off += (size_t)M * HID * 2;    // 12.8MB
    float*          bias4 = (float*)(ws + off);          off += (size_t)128 * 4 * 4;    // 2KB
    unsigned short* S     = (unsigned short*)(ws + off); off += (size_t)M * 512 * 2;    // 51.2MB
    unsigned short* Wcat  = (unsigned short*)(ws + off); off += (size_t)128 * 512 * 2;  // 128KB
    unsigned short* Wgru  = (unsigned short*)(ws + off); off += (size_t)512 * 256 * 2;  // 256KB
    float*          cnt4  = (float*)(ws + off);          off += (size_t)M * 4 * 4;      // 800KB
    int* deg4     = (int*)(ws + off); off += (size_t)N4 * 4;
    int* rowptr4  = (int*)(ws + off); off += (size_t)(N4 + 1) * 4;
    int* cursor4  = (int*)(ws + off); off += (size_t)N4 * 4;
    int* blocksum = (int*)(ws + off); off += 256 * 4;
    int* blockoff = (int*)(ws + off); off += 256 * 4;
    int* csr      = (int*)(ws + off); off += (size_t)E * 4;

    const int total4 = M * HID / 4;
    const int nb_cvt = (total4 + 255) / 256;     // 6250
    const int nb_zero = (N4 + 255) / 256;        // 782
    const int nb_scan = (N4 + 1023) / 1024;      // 196 <= 256

    prep_kernel<<<nb_cvt + 769 + nb_zero, 256, 0, stream>>>(
        node_states, hbf, edge_W, Wcat, w_ih, w_hh, Wgru, bias4, b_ih, b_hh,
        deg4, total4, nb_cvt, N4);

    hist4_kernel<<<(E + 255) / 256, 256, 0, stream>>>(dst, edge_type, deg4, E);
    scan_blocks4_kernel<<<nb_scan, 256, 0, stream>>>(deg4, rowptr4, blocksum, N4);
    scan_top_kernel<<<1, 256, 0, stream>>>(blocksum, blockoff, nb_scan);
    finalize4_kernel<<<(N4 + 255) / 256, 256, 0, stream>>>(rowptr4, blockoff, cursor4, N4, E);
    fill4_kernel<<<(E + 255) / 256, 256, 0, stream>>>(src, dst, edge_type, cursor4, csr, E);

    gather_s_kernel<<<(M + 3) / 4, 256, 0, stream>>>(rowptr4, csr, (const unsigned int*)hbf,
                                                     (float4*)cnt4, (unsigned int*)S, M);

    agg_gru<<<(M + 63) / 64, 512, 0, stream>>>(S, Wcat, Wgru, hbf, (const float4*)cnt4,
                                               edge_b, (const float4*)bias4, (float*)d_out, M);
}